// Round 10
// baseline (369.737 us; speedup 1.0000x reference)
//
#include <hip/hip_runtime.h>

typedef __bf16 bf16_t;
typedef __bf16 bf16x8 __attribute__((ext_vector_type(8)));
typedef float f32x4 __attribute__((ext_vector_type(4)));
typedef unsigned short ushort_t;

#define MFMA_16x16x32(a, b, c) __builtin_amdgcn_mfma_f32_16x16x32_bf16((a), (b), (c), 0, 0, 0)

// async global->LDS, 16B per lane. LDS dest must be wave-uniform; HW adds lane*16.
__device__ __forceinline__ void async_ld16(const void* gptr, void* lptr) {
  typedef __attribute__((address_space(1))) const unsigned int as1_t;
  typedef __attribute__((address_space(3))) unsigned int as3_t;
  __builtin_amdgcn_global_load_lds((as1_t*)(unsigned long long)gptr,
                                   (as3_t*)(unsigned int)(unsigned long long)lptr,
                                   16, 0, 0);
}

__device__ __forceinline__ unsigned int pack_bf16x2(float a, float b) {
  unsigned int lo = __builtin_bit_cast(unsigned short, (bf16_t)a);
  unsigned int hi = __builtin_bit_cast(unsigned short, (bf16_t)b);
  return lo | (hi << 16);
}

// ---------------------------------------------------------------------------
// Input-dtype detector (f32-read-as-bf16 has ~47% wild exponents in low halves).
// ---------------------------------------------------------------------------
__global__ void detect_dtype(const ushort_t* __restrict__ x, int* __restrict__ flag) {
  __shared__ int cnt[256];
  int c = 0;
#pragma unroll
  for (int i = 0; i < 16; ++i) {
    const ushort_t u = x[threadIdx.x * 16 + i];
    const int e = (u >> 7) & 0xFF;
    if ((u & 0x7FFF) != 0 && (e < 0x3A || e > 0xC0)) ++c;
  }
  cnt[threadIdx.x] = c;
  __syncthreads();
  if (threadIdx.x == 0) {
    int t = 0;
    for (int i = 0; i < 256; ++i) t += cnt[i];
    *flag = (t > 512) ? 1 : 0;
  }
}

// ---------------------------------------------------------------------------
// Normalize input to bf16 (flag==1: f32 src; else 16B copy). n8 = elems/8.
// ---------------------------------------------------------------------------
__global__ __launch_bounds__(256) void convert_to_bf16(const void* __restrict__ src,
                                                       bf16_t* __restrict__ dst, int n8,
                                                       const int* __restrict__ flag) {
  const int isF32 = *flag;
  int i = blockIdx.x * 256 + threadIdx.x;
  const int stride = gridDim.x * 256;
  if (isF32) {
    const float4* s = (const float4*)src;
    for (; i < n8; i += stride) {
      const float4 a = s[(size_t)i * 2];
      const float4 b = s[(size_t)i * 2 + 1];
      bf16x8 o;
      o[0] = (bf16_t)a.x; o[1] = (bf16_t)a.y; o[2] = (bf16_t)a.z; o[3] = (bf16_t)a.w;
      o[4] = (bf16_t)b.x; o[5] = (bf16_t)b.y; o[6] = (bf16_t)b.z; o[7] = (bf16_t)b.w;
      *(bf16x8*)(dst + (size_t)i * 8) = o;
    }
  } else {
    const uint4* s = (const uint4*)src;
    for (; i < n8; i += stride) ((uint4*)dst)[i] = s[i];
  }
}

// ---------------------------------------------------------------------------
// Fused convert + 64x64 transpose for weights: in (f32 or bf16 per flag)
// [R][C] -> out bf16 [C][R].
// ---------------------------------------------------------------------------
__global__ __launch_bounds__(256) void transpose_cvt(const void* __restrict__ in,
                                                     ushort_t* __restrict__ out,
                                                     int R, int C,
                                                     const int* __restrict__ flag) {
  __shared__ alignas(16) ushort_t t[64 * 72];
  const int tid = threadIdx.x;
  const int c0 = blockIdx.x * 64;
  const int r0 = blockIdx.y * 64;
  if (*flag) {
    const float* s = (const float*)in;
#pragma unroll
    for (int it = 0; it < 4; ++it) {
      int cid = tid + it * 256;            // 0..1023
      int row = cid >> 4, ch = (cid & 15) * 4;  // 4 f32 per chunk
      const float4 v = *(const float4*)(s + (size_t)(r0 + row) * C + c0 + ch);
      ushort_t* tp = t + row * 72 + ch;
      tp[0] = (ushort_t)__builtin_bit_cast(unsigned short, (bf16_t)v.x);
      tp[1] = (ushort_t)__builtin_bit_cast(unsigned short, (bf16_t)v.y);
      tp[2] = (ushort_t)__builtin_bit_cast(unsigned short, (bf16_t)v.z);
      tp[3] = (ushort_t)__builtin_bit_cast(unsigned short, (bf16_t)v.w);
    }
  } else {
    const ushort_t* s = (const ushort_t*)in;
#pragma unroll
    for (int it = 0; it < 2; ++it) {
      int cid = tid + it * 256;
      int row = cid >> 3, co = (cid & 7) * 8;
      *(uint4*)(t + row * 72 + co) = *(const uint4*)(s + (size_t)(r0 + row) * C + c0 + co);
    }
  }
  __syncthreads();
#pragma unroll
  for (int it = 0; it < 2; ++it) {
    int cid = tid + it * 256;
    int orow = cid >> 3, ko = (cid & 7) * 8;
    uint4 u;
    ushort_t* tp = (ushort_t*)&u;
#pragma unroll
    for (int j = 0; j < 8; ++j) tp[j] = t[(ko + j) * 72 + orow];
    *(uint4*)(out + (size_t)(c0 + orow) * R + r0 + ko) = u;
  }
}

// ---------------------------------------------------------------------------
// GEMM core: C[M][N] = A[M][K] * Bt[N][K]^T.  256x256 tile, BK=32, 8 waves,
// 512 threads, TRIPLE-buffered LDS, 1 barrier + counted vmcnt(4) per K-tile.
// V-FUSION (vT != nullptr, tn >= 2048): V cols stored transposed via LDS
// aggregation.  R10: packed b64 LDS writes (4 scalar -> 1 uint2) and
// group-PAIRS in two LDS tiles -> 4 barriers instead of 8.
// ---------------------------------------------------------------------------
__device__ __forceinline__ void gemm_core(const bf16_t* __restrict__ A, int lda,
                                          const bf16_t* __restrict__ Bt,
                                          void* __restrict__ Cout, int N_out, int K,
                                          const int* __restrict__ flag,
                                          bf16_t* __restrict__ vT) {
  __shared__ alignas(16) bf16_t smem[49152];  // 96 KiB: 3 x [A 8K | B 8K] elems
  const int tid = threadIdx.x;
  const int wave = tid >> 6;
  const int lane = tid & 63;
  const int l15 = lane & 15;
  const int quad = lane >> 4;
  const int wm = wave >> 2;  // 0..1
  const int wn = wave & 3;   // 0..3

  int lin = blockIdx.y * gridDim.x + blockIdx.x;
  const int nwg = gridDim.x * gridDim.y;
  if ((nwg & 7) == 0) lin = (lin & 7) * (nwg >> 3) + (lin >> 3);
  const int tn = (lin % gridDim.x) * 256;
  const int tm = (lin / gridDim.x) * 256;

  f32x4 acc[8][4];
#pragma unroll
  for (int i = 0; i < 8; ++i)
#pragma unroll
    for (int j = 0; j < 4; ++j) acc[i][j] = (f32x4){0.f, 0.f, 0.f, 0.f};

  const int r_st = tid >> 2;
  const int csrc = ((tid & 3) ^ ((tid >> 3) & 3)) * 8;
  const int wofs = wave * 512;

  const int rowA = wm * 16 + l15;
  const int rowB = wn * 16 + l15;
  const int cfr = (quad ^ ((l15 >> 1) & 3)) * 8;

  const int NT = K >> 5;

#define STAGE_HALF(G, ldg, grow0, kk, base)                                  \
  async_ld16((G) + (size_t)((grow0) + r_st) * (ldg) + (kk) + csrc,           \
             &smem[(base) + wofs])

#define STAGE4(kk, base)                                \
  do {                                                  \
    STAGE_HALF(A, lda, tm, (kk), (base));               \
    STAGE_HALF(Bt, K, tn, (kk), (base) + 8192);         \
    STAGE_HALF(Bt, K, tn + 128, (kk), (base) + 12288);  \
    STAGE_HALF(A, lda, tm + 128, (kk), (base) + 4096);  \
  } while (0)

  STAGE4(0, 0);
  STAGE4(32, 16384);
  asm volatile("s_waitcnt vmcnt(4)" ::: "memory");
  __builtin_amdgcn_s_barrier();

  int rb = 0;
  for (int t = 0; t < NT; ++t) {
    const int kst = (t + 2) << 5;
    const bool pf = (kst < K);
    const int sb = (rb >= 16384) ? rb - 16384 : rb + 32768;
    if (pf) STAGE4(kst, sb);

    bf16x8 a_[8], b_[4];
#pragma unroll
    for (int mh = 0; mh < 2; ++mh)
#pragma unroll
      for (int q = 0; q < 4; ++q)
        a_[mh * 4 + q] = *(const bf16x8*)&smem[rb + mh * 4096 +
                                               ((q * 32 + rowA) << 5) + cfr];
#pragma unroll
    for (int nh = 0; nh < 2; ++nh)
#pragma unroll
      for (int jn = 0; jn < 2; ++jn)
        b_[nh * 2 + jn] = *(const bf16x8*)&smem[rb + 8192 + nh * 4096 +
                                                ((jn * 64 + rowB) << 5) + cfr];

    __builtin_amdgcn_s_setprio(1);
#pragma unroll
    for (int f = 0; f < 8; ++f)
#pragma unroll
      for (int n = 0; n < 4; ++n) acc[f][n] = MFMA_16x16x32(a_[f], b_[n], acc[f][n]);
    __builtin_amdgcn_s_setprio(0);

    asm volatile("s_waitcnt vmcnt(4)" ::: "memory");
    if (!pf) asm volatile("s_waitcnt vmcnt(0)" ::: "memory");
    __builtin_amdgcn_s_barrier();
    rb = (rb == 32768) ? 0 : rb + 16384;
  }

  __syncthreads();

  const int isF32 = flag ? *flag : 0;
  if (isF32) {
#pragma unroll
    for (int f = 0; f < 8; ++f) {
      const int m0 = tm + (f >> 2) * 128 + (f & 3) * 32 + wm * 16 + quad * 4;
#pragma unroll
      for (int nidx = 0; nidx < 4; ++nidx) {
        const int col = tn + (nidx >> 1) * 128 + (nidx & 1) * 64 + wn * 16 + l15;
        float* cp = (float*)Cout + (size_t)m0 * N_out + col;
#pragma unroll
        for (int r = 0; r < 4; ++r) cp[(size_t)r * N_out] = acc[f][nidx][r];
      }
    }
  } else if (vT != nullptr && tn >= 2048) {
    // V blocks: aggregate group-PAIRS through two LDS [64][264] tiles; packed
    // b64 LDS writes; 64B-contiguous global stores (8 threads = 512B run/col).
    const int bb = tm >> 12;
    const int pbase = tm & 4095;
    bf16_t* stg = smem;  // 2 x 16896 elems = 66 KB of 96 KB
    const int colp = wn * 16 + l15;
    const int colr = tid >> 3;
    const int p0 = (tid & 7) * 32;
#pragma unroll
    for (int gp = 0; gp < 2; ++gp) {
      __syncthreads();
#pragma unroll
      for (int half = 0; half < 2; ++half) {
        const int g = gp * 2 + half;
        bf16_t* tile = stg + half * 16896;
#pragma unroll
        for (int f = 0; f < 8; ++f) {
          const int posl = (f >> 2) * 128 + (f & 3) * 32 + wm * 16 + quad * 4;
          uint2 u;
          u.x = pack_bf16x2(acc[f][g][0], acc[f][g][1]);
          u.y = pack_bf16x2(acc[f][g][2], acc[f][g][3]);
          *(uint2*)(tile + colp * 264 + posl) = u;
        }
      }
      __syncthreads();
#pragma unroll
      for (int half = 0; half < 2; ++half) {
        const int g = gp * 2 + half;
        const int cg = tn - 2048 + (g >> 1) * 128 + ((g & 1) << 6) + colr;
        const bf16_t* srcp = stg + half * 16896 + colr * 264 + p0;
        bf16_t* dst = vT + ((size_t)(bb * 1024 + cg)) * 4096 + pbase + p0;
#pragma unroll
        for (int k = 0; k < 4; ++k)
          *(uint4*)(dst + k * 8) = *(const uint4*)(srcp + k * 8);
      }
    }
  } else {
    bf16_t* stg = smem + wave * 1152;
#pragma unroll
    for (int f = 0; f < 8; ++f) {
#pragma unroll
      for (int nidx = 0; nidx < 4; ++nidx)
#pragma unroll
        for (int r = 0; r < 4; ++r)
          stg[(quad * 4 + r) * 72 + nidx * 16 + l15] = (bf16_t)acc[f][nidx][r];
      __asm__ volatile("s_waitcnt lgkmcnt(0)" ::: "memory");
      const int m0 = tm + (f >> 2) * 128 + (f & 3) * 32 + wm * 16;
#pragma unroll
      for (int p = 0; p < 2; ++p) {
        const int idx = lane + p * 64;
        const int row = idx >> 3, c8 = (idx & 7) * 8;
        uint4 u = *(const uint4*)(stg + row * 72 + c8);
        const int col = tn + ((c8 >> 5) << 7) + (((c8 >> 4) & 1) << 6) + wn * 16 + (c8 & 15);
        *(uint4*)((bf16_t*)Cout + (size_t)(m0 + row) * N_out + col) = u;
      }
      __asm__ volatile("s_waitcnt lgkmcnt(0)" ::: "memory");
    }
  }
#undef STAGE_HALF
#undef STAGE4
}

// Distinct names so rocprof rows disambiguate.
__global__ __launch_bounds__(512) void gemm_qkv(const bf16_t* __restrict__ A, int lda,
                                                const bf16_t* __restrict__ Bt,
                                                void* __restrict__ Cout, int N_out,
                                                int K, bf16_t* __restrict__ vT) {
  gemm_core(A, lda, Bt, Cout, N_out, K, nullptr, vT);
}
__global__ __launch_bounds__(512) void gemm_outp(const bf16_t* __restrict__ A, int lda,
                                                 const bf16_t* __restrict__ Bt,
                                                 void* __restrict__ Cout, int N_out,
                                                 int K, const int* __restrict__ flag) {
  gemm_core(A, lda, Bt, Cout, N_out, K, flag, nullptr);
}

// ---------------------------------------------------------------------------
// Sliding-window attention.  R10: 128 queries per workgroup (4 waves x 32
// rows, 2 row-groups of 16 per wave) -> K/V chunk loads per 128 queries drop
// from 10 (2 x 64q tiles) to 6: 1.67x less K/V traffic (attn is traffic-bound:
// ~393 MB at the L2/HBM mix ~= the observed ~110 us).  Same chunk pipeline,
// straight-line softmax, reg-prefetch, setprio as the proven R2 structure.
// qkv: [b*4096+pos][3072] (Q at h*64, K at 1024+h*64; O overwrites Q cols).
// vT: [b][h][d][4096].  Grid: 2048 = 4 b x 16 h x 8 qt... (32 qt of 128).
// ---------------------------------------------------------------------------
__global__ __launch_bounds__(256) void attn_swa(bf16_t* qkv, const bf16_t* __restrict__ vT) {
  __shared__ alignas(16) bf16_t k_lds[64 * 72];   // [key][d]
  __shared__ alignas(16) bf16_t vt_lds[64 * 72];  // [d][key]
  __shared__ alignas(16) bf16_t p_lds[4 * 2 * 16 * 72];  // [wave][rg][16][72]

  // XCD swizzle: 256 consecutive logical wgs (8 (b,h) pairs) per XCD.
  int wg = blockIdx.x;
  wg = (wg & 7) * 256 + (wg >> 3);
  const int b = wg >> 9;
  const int h = (wg >> 5) & 15;
  const int qt = wg & 31;  // 128-query tile index
  const int tid = threadIdx.x;
  const int wave = tid >> 6;
  const int lane = tid & 63;
  const int l15 = lane & 15;
  const int quad = lane >> 4;
  const int qw = qt * 128 + wave * 32;  // this wave's first query row

  // Q fragments for both 16-row groups.
  bf16x8 qf[2][2];
#pragma unroll
  for (int rg = 0; rg < 2; ++rg) {
    const size_t qoff = ((size_t)(b * 4096 + qw + rg * 16 + l15)) * 3072 + h * 64;
    qf[rg][0] = *(const bf16x8*)(qkv + qoff + quad * 8);
    qf[rg][1] = *(const bf16x8*)(qkv + qoff + 32 + quad * 8);
  }

  f32x4 of[2][4];
#pragma unroll
  for (int rg = 0; rg < 2; ++rg)
#pragma unroll
    for (int i = 0; i < 4; ++i) of[rg][i] = (f32x4){0.f, 0.f, 0.f, 0.f};
  float m_i[2][4], l_i[2][4];
#pragma unroll
  for (int rg = 0; rg < 2; ++rg)
#pragma unroll
    for (int r = 0; r < 4; ++r) {
      m_i[rg][r] = -1e30f;
      l_i[rg][r] = 0.0f;
    }

  // chunks kc=0..5 cover keys [qt*128-256, qt*128+127]; clip kb >= 0.
  const int kb0 = qt * 128 - 256;
  const int kclo = (qt == 0) ? 4 : ((qt == 1) ? 2 : 0);
  const int kchi = 5;

  const int row0 = tid >> 3;
  const int co8 = (tid & 7) * 8;
  const bf16_t* kbase = qkv + ((size_t)b * 4096) * 3072 + 1024 + h * 64;
  const bf16_t* vbase = vT + (((size_t)b * 16 + h) * 64) * 4096;
  uint4 kr0, kr1, vr0, vr1;

#define ISSUE_KV(KB)                                                           \
  do {                                                                         \
    kr0 = *(const uint4*)(kbase + (size_t)((KB) + row0) * 3072 + co8);         \
    kr1 = *(const uint4*)(kbase + (size_t)((KB) + row0 + 32) * 3072 + co8);    \
    vr0 = *(const uint4*)(vbase + (size_t)row0 * 4096 + (KB) + co8);           \
    vr1 = *(const uint4*)(vbase + (size_t)(row0 + 32) * 4096 + (KB) + co8);    \
  } while (0)

  ISSUE_KV(kb0 + kclo * 64);

  for (int kc = kclo; kc <= kchi; ++kc) {
    const int kb = kb0 + kc * 64;
    __syncthreads();  // prev chunk's PV reads done -> LDS reusable
    *(uint4*)(k_lds + row0 * 72 + co8) = kr0;
    *(uint4*)(k_lds + (row0 + 32) * 72 + co8) = kr1;
    *(uint4*)(vt_lds + row0 * 72 + co8) = vr0;
    *(uint4*)(vt_lds + (row0 + 32) * 72 + co8) = vr1;
    if (kc < kchi) ISSUE_KV(kb + 64);  // in flight under QK+softmax+PV
    __syncthreads();

    f32x4 s[2][4];
    __builtin_amdgcn_s_setprio(1);
#pragma unroll
    for (int nt = 0; nt < 4; ++nt) {
      bf16x8 kf0 = *(const bf16x8*)(k_lds + (nt * 16 + l15) * 72 + quad * 8);
      bf16x8 kf1 = *(const bf16x8*)(k_lds + (nt * 16 + l15) * 72 + 32 + quad * 8);
#pragma unroll
      for (int rg = 0; rg < 2; ++rg) {
        f32x4 z = (f32x4){0.f, 0.f, 0.f, 0.f};
        z = MFMA_16x16x32(qf[rg][0], kf0, z);
        z = MFMA_16x16x32(qf[rg][1], kf1, z);
        s[rg][nt] = z;
      }
    }
    __builtin_amdgcn_s_setprio(0);

    float sv[2][4][4];
#pragma unroll
    for (int nt = 0; nt < 4; ++nt) {
      const int key = kb + nt * 16 + l15;
#pragma unroll
      for (int rg = 0; rg < 2; ++rg)
#pragma unroll
        for (int r = 0; r < 4; ++r) {
          const int p = qw + rg * 16 + quad * 4 + r;
          const bool valid = (key <= p) && (key + 256 > p);
          sv[rg][nt][r] = valid ? s[rg][nt][r] * 0.125f : -1e30f;
        }
    }
    float rm[2][4];
#pragma unroll
    for (int rg = 0; rg < 2; ++rg)
#pragma unroll
      for (int r = 0; r < 4; ++r)
        rm[rg][r] = fmaxf(fmaxf(sv[rg][0][r], sv[rg][1][r]),
                          fmaxf(sv[rg][2][r], sv[rg][3][r]));
#pragma unroll
    for (int off = 1; off < 16; off <<= 1)
#pragma unroll
      for (int rg = 0; rg < 2; ++rg)
#pragma unroll
        for (int r = 0; r < 4; ++r) rm[rg][r] = fmaxf(rm[rg][r], __shfl_xor(rm[rg][r], off));

    float mn[2][4], alpha[2][4];
#pragma unroll
    for (int rg = 0; rg < 2; ++rg)
#pragma unroll
      for (int r = 0; r < 4; ++r) {
        mn[rg][r] = fmaxf(m_i[rg][r], rm[rg][r]);
        alpha[rg][r] = __expf(m_i[rg][r] - mn[rg][r]);
        m_i[rg][r] = mn[rg][r];
      }

    float rs[2][4] = {{0.f, 0.f, 0.f, 0.f}, {0.f, 0.f, 0.f, 0.f}};
#pragma unroll
    for (int nt = 0; nt < 4; ++nt)
#pragma unroll
      for (int rg = 0; rg < 2; ++rg)
#pragma unroll
        for (int r = 0; r < 4; ++r) {
          const float pv = (sv[rg][nt][r] > -1e29f) ? __expf(sv[rg][nt][r] - mn[rg][r]) : 0.0f;
          rs[rg][r] += pv;
          p_lds[(wave * 2 + rg) * 1152 + (quad * 4 + r) * 72 + nt * 16 + l15] = (bf16_t)pv;
        }
#pragma unroll
    for (int off = 1; off < 16; off <<= 1)
#pragma unroll
      for (int rg = 0; rg < 2; ++rg)
#pragma unroll
        for (int r = 0; r < 4; ++r) rs[rg][r] += __shfl_xor(rs[rg][r], off);
#pragma unroll
    for (int rg = 0; rg < 2; ++rg)
#pragma unroll
      for (int r = 0; r < 4; ++r) l_i[rg][r] = l_i[rg][r] * alpha[rg][r] + rs[rg][r];
#pragma unroll
    for (int rg = 0; rg < 2; ++rg)
#pragma unroll
      for (int dt = 0; dt < 4; ++dt)
#pragma unroll
        for (int r = 0; r < 4; ++r) of[rg][dt][r] *= alpha[rg][r];

    // p_lds slice is wave-private (write->read same wave, lgkmcnt-ordered).
    __builtin_amdgcn_s_setprio(1);
#pragma unroll
    for (int kk = 0; kk < 2; ++kk) {
#pragma unroll
      for (int rg = 0; rg < 2; ++rg) {
        bf16x8 pf = *(const bf16x8*)(p_lds + (wave * 2 + rg) * 1152 + l15 * 72 +
                                     kk * 32 + quad * 8);
#pragma unroll
        for (int dt = 0; dt < 4; ++dt) {
          bf16x8 vf = *(const bf16x8*)(vt_lds + (dt * 16 + l15) * 72 + kk * 32 + quad * 8);
          of[rg][dt] = MFMA_16x16x32(pf, vf, of[rg][dt]);
        }
      }
    }
    __builtin_amdgcn_s_setprio(0);
  }
#undef ISSUE_KV

#pragma unroll
  for (int rg = 0; rg < 2; ++rg) {
    float inv[4];
#pragma unroll
    for (int r = 0; r < 4; ++r) inv[r] = 1.0f / fmaxf(l_i[rg][r], 1e-20f);
    bf16_t* op = qkv + ((size_t)(b * 4096 + qw + rg * 16)) * 3072 + h * 64;
#pragma unroll
    for (int dt = 0; dt < 4; ++dt)
#pragma unroll
      for (int r = 0; r < 4; ++r)
        op[(size_t)(quad * 4 + r) * 3072 + dt * 16 + l15] = (bf16_t)(of[rg][dt][r] * inv[r]);
  }
}

// ---------------------------------------------------------------------------
extern "C" void kernel_launch(void* const* d_in, const int* in_sizes, int n_in,
                              void* d_out, int out_size, void* d_ws, size_t ws_size,
                              hipStream_t stream) {
  char* ws = (char*)d_ws;
  bf16_t* wTq = (bf16_t*)(ws);                    // [3072][1024]   6,291,456 B
  bf16_t* wTo = (bf16_t*)(ws + 6291456);          // [1024][1024]   2,097,152 B
  bf16_t* qkv = (bf16_t*)(ws + 8388608);          // [16384][3072] 100,663,296 B
  int* flag = (int*)(ws + 109051904);             // 4 B (total 109,051,908 B)

  bf16_t* xb = (bf16_t*)d_out;                    // converted x, [0, 32MB)
  bf16_t* vTb = (bf16_t*)((char*)d_out + 33554432);  // vT, [32MB, 64MB)
  // xb consumed by QKV GEMM (which writes vT into the other half of d_out);
  // vT consumed by attention; final GEMM overwrites all of d_out with f32.

  detect_dtype<<<1, 256, 0, stream>>>((const ushort_t*)d_in[0], flag);
  convert_to_bf16<<<1024, 256, 0, stream>>>(d_in[0], xb, 2097152, flag);
  transpose_cvt<<<dim3(48, 16), 256, 0, stream>>>(d_in[1], (ushort_t*)wTq, 1024, 3072,
                                                  flag);
  transpose_cvt<<<dim3(16, 16), 256, 0, stream>>>(d_in[2], (ushort_t*)wTo, 1024, 1024,
                                                  flag);
  // QKV GEMM with fused V-transpose (V cols -> vTb, Q/K cols -> qkv)
  gemm_qkv<<<dim3(12, 64), 512, 0, stream>>>(xb, 1024, wTq, qkv, 3072, 1024, vTb);
  attn_swa<<<dim3(2048), 256, 0, stream>>>(qkv, vTb);
  gemm_outp<<<dim3(4, 64), 512, 0, stream>>>(qkv, 3072, wTo, d_out, 1024, 1024, flag);
}

// Round 11
// 353.994 us; speedup vs baseline: 1.0445x; 1.0445x over previous
//
#include <hip/hip_runtime.h>

typedef __bf16 bf16_t;
typedef __bf16 bf16x8 __attribute__((ext_vector_type(8)));
typedef float f32x4 __attribute__((ext_vector_type(4)));
typedef unsigned short ushort_t;

#define MFMA_16x16x32(a, b, c) __builtin_amdgcn_mfma_f32_16x16x32_bf16((a), (b), (c), 0, 0, 0)

// async global->LDS, 16B per lane. LDS dest must be wave-uniform; HW adds lane*16.
__device__ __forceinline__ void async_ld16(const void* gptr, void* lptr) {
  typedef __attribute__((address_space(1))) const unsigned int as1_t;
  typedef __attribute__((address_space(3))) unsigned int as3_t;
  __builtin_amdgcn_global_load_lds((as1_t*)(unsigned long long)gptr,
                                   (as3_t*)(unsigned int)(unsigned long long)lptr,
                                   16, 0, 0);
}

__device__ __forceinline__ unsigned int pack_bf16x2(float a, float b) {
  unsigned int lo = __builtin_bit_cast(unsigned short, (bf16_t)a);
  unsigned int hi = __builtin_bit_cast(unsigned short, (bf16_t)b);
  return lo | (hi << 16);
}

// ---------------------------------------------------------------------------
// Input-dtype detector (f32-read-as-bf16 has ~47% wild exponents in low halves).
// ---------------------------------------------------------------------------
__global__ void detect_dtype(const ushort_t* __restrict__ x, int* __restrict__ flag) {
  __shared__ int cnt[256];
  int c = 0;
#pragma unroll
  for (int i = 0; i < 16; ++i) {
    const ushort_t u = x[threadIdx.x * 16 + i];
    const int e = (u >> 7) & 0xFF;
    if ((u & 0x7FFF) != 0 && (e < 0x3A || e > 0xC0)) ++c;
  }
  cnt[threadIdx.x] = c;
  __syncthreads();
  if (threadIdx.x == 0) {
    int t = 0;
    for (int i = 0; i < 256; ++i) t += cnt[i];
    *flag = (t > 512) ? 1 : 0;
  }
}

// ---------------------------------------------------------------------------
// Normalize input to bf16 (flag==1: f32 src; else 16B copy). n8 = elems/8.
// ---------------------------------------------------------------------------
__global__ __launch_bounds__(256) void convert_to_bf16(const void* __restrict__ src,
                                                       bf16_t* __restrict__ dst, int n8,
                                                       const int* __restrict__ flag) {
  const int isF32 = *flag;
  int i = blockIdx.x * 256 + threadIdx.x;
  const int stride = gridDim.x * 256;
  if (isF32) {
    const float4* s = (const float4*)src;
    for (; i < n8; i += stride) {
      const float4 a = s[(size_t)i * 2];
      const float4 b = s[(size_t)i * 2 + 1];
      bf16x8 o;
      o[0] = (bf16_t)a.x; o[1] = (bf16_t)a.y; o[2] = (bf16_t)a.z; o[3] = (bf16_t)a.w;
      o[4] = (bf16_t)b.x; o[5] = (bf16_t)b.y; o[6] = (bf16_t)b.z; o[7] = (bf16_t)b.w;
      *(bf16x8*)(dst + (size_t)i * 8) = o;
    }
  } else {
    const uint4* s = (const uint4*)src;
    for (; i < n8; i += stride) ((uint4*)dst)[i] = s[i];
  }
}

// ---------------------------------------------------------------------------
// Fused convert + 64x64 transpose for weights: in (f32 or bf16 per flag)
// [R][C] -> out bf16 [C][R].
// ---------------------------------------------------------------------------
__global__ __launch_bounds__(256) void transpose_cvt(const void* __restrict__ in,
                                                     ushort_t* __restrict__ out,
                                                     int R, int C,
                                                     const int* __restrict__ flag) {
  __shared__ alignas(16) ushort_t t[64 * 72];
  const int tid = threadIdx.x;
  const int c0 = blockIdx.x * 64;
  const int r0 = blockIdx.y * 64;
  if (*flag) {
    const float* s = (const float*)in;
#pragma unroll
    for (int it = 0; it < 4; ++it) {
      int cid = tid + it * 256;            // 0..1023
      int row = cid >> 4, ch = (cid & 15) * 4;  // 4 f32 per chunk
      const float4 v = *(const float4*)(s + (size_t)(r0 + row) * C + c0 + ch);
      ushort_t* tp = t + row * 72 + ch;
      tp[0] = (ushort_t)__builtin_bit_cast(unsigned short, (bf16_t)v.x);
      tp[1] = (ushort_t)__builtin_bit_cast(unsigned short, (bf16_t)v.y);
      tp[2] = (ushort_t)__builtin_bit_cast(unsigned short, (bf16_t)v.z);
      tp[3] = (ushort_t)__builtin_bit_cast(unsigned short, (bf16_t)v.w);
    }
  } else {
    const ushort_t* s = (const ushort_t*)in;
#pragma unroll
    for (int it = 0; it < 2; ++it) {
      int cid = tid + it * 256;
      int row = cid >> 3, co = (cid & 7) * 8;
      *(uint4*)(t + row * 72 + co) = *(const uint4*)(s + (size_t)(r0 + row) * C + c0 + co);
    }
  }
  __syncthreads();
#pragma unroll
  for (int it = 0; it < 2; ++it) {
    int cid = tid + it * 256;
    int orow = cid >> 3, ko = (cid & 7) * 8;
    uint4 u;
    ushort_t* tp = (ushort_t*)&u;
#pragma unroll
    for (int j = 0; j < 8; ++j) tp[j] = t[(ko + j) * 72 + orow];
    *(uint4*)(out + (size_t)(c0 + orow) * R + r0 + ko) = u;
  }
}

// ---------------------------------------------------------------------------
// GEMM core: C[M][N] = A[M][K] * Bt[N][K]^T.  256x256 tile, BK=32, 8 waves,
// 512 threads, TRIPLE-buffered LDS, 1 barrier + counted vmcnt(4) per K-tile.
// V-FUSION (vT != nullptr, tn >= 2048): V cols stored transposed via LDS
// aggregation; packed b64 LDS writes, group-pairs in two tiles (4 barriers).
// Measured (R10): QKV 116.8 us, FETCH 94.3 MB, WRITE 98.4 MB.
// ---------------------------------------------------------------------------
__device__ __forceinline__ void gemm_core(const bf16_t* __restrict__ A, int lda,
                                          const bf16_t* __restrict__ Bt,
                                          void* __restrict__ Cout, int N_out, int K,
                                          const int* __restrict__ flag,
                                          bf16_t* __restrict__ vT) {
  __shared__ alignas(16) bf16_t smem[49152];  // 96 KiB: 3 x [A 8K | B 8K] elems
  const int tid = threadIdx.x;
  const int wave = tid >> 6;
  const int lane = tid & 63;
  const int l15 = lane & 15;
  const int quad = lane >> 4;
  const int wm = wave >> 2;  // 0..1
  const int wn = wave & 3;   // 0..3

  int lin = blockIdx.y * gridDim.x + blockIdx.x;
  const int nwg = gridDim.x * gridDim.y;
  if ((nwg & 7) == 0) lin = (lin & 7) * (nwg >> 3) + (lin >> 3);
  const int tn = (lin % gridDim.x) * 256;
  const int tm = (lin / gridDim.x) * 256;

  f32x4 acc[8][4];
#pragma unroll
  for (int i = 0; i < 8; ++i)
#pragma unroll
    for (int j = 0; j < 4; ++j) acc[i][j] = (f32x4){0.f, 0.f, 0.f, 0.f};

  const int r_st = tid >> 2;
  const int csrc = ((tid & 3) ^ ((tid >> 3) & 3)) * 8;
  const int wofs = wave * 512;

  const int rowA = wm * 16 + l15;
  const int rowB = wn * 16 + l15;
  const int cfr = (quad ^ ((l15 >> 1) & 3)) * 8;

  const int NT = K >> 5;

#define STAGE_HALF(G, ldg, grow0, kk, base)                                  \
  async_ld16((G) + (size_t)((grow0) + r_st) * (ldg) + (kk) + csrc,           \
             &smem[(base) + wofs])

#define STAGE4(kk, base)                                \
  do {                                                  \
    STAGE_HALF(A, lda, tm, (kk), (base));               \
    STAGE_HALF(Bt, K, tn, (kk), (base) + 8192);         \
    STAGE_HALF(Bt, K, tn + 128, (kk), (base) + 12288);  \
    STAGE_HALF(A, lda, tm + 128, (kk), (base) + 4096);  \
  } while (0)

  STAGE4(0, 0);
  STAGE4(32, 16384);
  asm volatile("s_waitcnt vmcnt(4)" ::: "memory");
  __builtin_amdgcn_s_barrier();

  int rb = 0;
  for (int t = 0; t < NT; ++t) {
    const int kst = (t + 2) << 5;
    const bool pf = (kst < K);
    const int sb = (rb >= 16384) ? rb - 16384 : rb + 32768;
    if (pf) STAGE4(kst, sb);

    bf16x8 a_[8], b_[4];
#pragma unroll
    for (int mh = 0; mh < 2; ++mh)
#pragma unroll
      for (int q = 0; q < 4; ++q)
        a_[mh * 4 + q] = *(const bf16x8*)&smem[rb + mh * 4096 +
                                               ((q * 32 + rowA) << 5) + cfr];
#pragma unroll
    for (int nh = 0; nh < 2; ++nh)
#pragma unroll
      for (int jn = 0; jn < 2; ++jn)
        b_[nh * 2 + jn] = *(const bf16x8*)&smem[rb + 8192 + nh * 4096 +
                                                ((jn * 64 + rowB) << 5) + cfr];

    __builtin_amdgcn_s_setprio(1);
#pragma unroll
    for (int f = 0; f < 8; ++f)
#pragma unroll
      for (int n = 0; n < 4; ++n) acc[f][n] = MFMA_16x16x32(a_[f], b_[n], acc[f][n]);
    __builtin_amdgcn_s_setprio(0);

    asm volatile("s_waitcnt vmcnt(4)" ::: "memory");
    if (!pf) asm volatile("s_waitcnt vmcnt(0)" ::: "memory");
    __builtin_amdgcn_s_barrier();
    rb = (rb == 32768) ? 0 : rb + 16384;
  }

  __syncthreads();

  const int isF32 = flag ? *flag : 0;
  if (isF32) {
#pragma unroll
    for (int f = 0; f < 8; ++f) {
      const int m0 = tm + (f >> 2) * 128 + (f & 3) * 32 + wm * 16 + quad * 4;
#pragma unroll
      for (int nidx = 0; nidx < 4; ++nidx) {
        const int col = tn + (nidx >> 1) * 128 + (nidx & 1) * 64 + wn * 16 + l15;
        float* cp = (float*)Cout + (size_t)m0 * N_out + col;
#pragma unroll
        for (int r = 0; r < 4; ++r) cp[(size_t)r * N_out] = acc[f][nidx][r];
      }
    }
  } else if (vT != nullptr && tn >= 2048) {
    // V blocks: aggregate group-PAIRS through two LDS [64][264] tiles; packed
    // b64 LDS writes; 64B-contiguous global stores (8 threads = 512B run/col).
    const int bb = tm >> 12;
    const int pbase = tm & 4095;
    bf16_t* stg = smem;  // 2 x 16896 elems = 66 KB of 96 KB
    const int colp = wn * 16 + l15;
    const int colr = tid >> 3;
    const int p0 = (tid & 7) * 32;
#pragma unroll
    for (int gp = 0; gp < 2; ++gp) {
      __syncthreads();
#pragma unroll
      for (int half = 0; half < 2; ++half) {
        const int g = gp * 2 + half;
        bf16_t* tile = stg + half * 16896;
#pragma unroll
        for (int f = 0; f < 8; ++f) {
          const int posl = (f >> 2) * 128 + (f & 3) * 32 + wm * 16 + quad * 4;
          uint2 u;
          u.x = pack_bf16x2(acc[f][g][0], acc[f][g][1]);
          u.y = pack_bf16x2(acc[f][g][2], acc[f][g][3]);
          *(uint2*)(tile + colp * 264 + posl) = u;
        }
      }
      __syncthreads();
#pragma unroll
      for (int half = 0; half < 2; ++half) {
        const int g = gp * 2 + half;
        const int cg = tn - 2048 + (g >> 1) * 128 + ((g & 1) << 6) + colr;
        const bf16_t* srcp = stg + half * 16896 + colr * 264 + p0;
        bf16_t* dst = vT + ((size_t)(bb * 1024 + cg)) * 4096 + pbase + p0;
#pragma unroll
        for (int k = 0; k < 4; ++k)
          *(uint4*)(dst + k * 8) = *(const uint4*)(srcp + k * 8);
      }
    }
  } else {
    bf16_t* stg = smem + wave * 1152;
#pragma unroll
    for (int f = 0; f < 8; ++f) {
#pragma unroll
      for (int nidx = 0; nidx < 4; ++nidx)
#pragma unroll
        for (int r = 0; r < 4; ++r)
          stg[(quad * 4 + r) * 72 + nidx * 16 + l15] = (bf16_t)acc[f][nidx][r];
      __asm__ volatile("s_waitcnt lgkmcnt(0)" ::: "memory");
      const int m0 = tm + (f >> 2) * 128 + (f & 3) * 32 + wm * 16;
#pragma unroll
      for (int p = 0; p < 2; ++p) {
        const int idx = lane + p * 64;
        const int row = idx >> 3, c8 = (idx & 7) * 8;
        uint4 u = *(const uint4*)(stg + row * 72 + c8);
        const int col = tn + ((c8 >> 5) << 7) + (((c8 >> 4) & 1) << 6) + wn * 16 + (c8 & 15);
        *(uint4*)((bf16_t*)Cout + (size_t)(m0 + row) * N_out + col) = u;
      }
      __asm__ volatile("s_waitcnt lgkmcnt(0)" ::: "memory");
    }
  }
#undef STAGE_HALF
#undef STAGE4
}

// Distinct names so rocprof rows disambiguate.
__global__ __launch_bounds__(512) void gemm_qkv(const bf16_t* __restrict__ A, int lda,
                                                const bf16_t* __restrict__ Bt,
                                                void* __restrict__ Cout, int N_out,
                                                int K, bf16_t* __restrict__ vT) {
  gemm_core(A, lda, Bt, Cout, N_out, K, nullptr, vT);
}
__global__ __launch_bounds__(512) void gemm_outp(const bf16_t* __restrict__ A, int lda,
                                                 const bf16_t* __restrict__ Bt,
                                                 void* __restrict__ Cout, int N_out,
                                                 int K, const int* __restrict__ flag) {
  gemm_core(A, lda, Bt, Cout, N_out, K, flag, nullptr);
}

// ---------------------------------------------------------------------------
// Sliding-window attention. R2 64-query version (best measured) — restored
// after the R10 128-query variant regressed +17 us (latency/VALU-bound at the
// block level; doubling serial per-wave work at lower occupancy lost).
// One workgroup = 64 queries of one (b,h); 4 waves x 16 rows; window = 5
// chunks of 64 keys. qkv: [b*4096+pos][3072] (Q at h*64, K at 1024+h*64;
// O overwrites the Q columns). vT: [b][h][d][4096].
// ---------------------------------------------------------------------------
__global__ __launch_bounds__(256) void attn_swa(bf16_t* qkv, const bf16_t* __restrict__ vT) {
  __shared__ alignas(16) bf16_t k_lds[64 * 72];   // [key][d]
  __shared__ alignas(16) bf16_t vt_lds[64 * 72];  // [d][key]
  __shared__ alignas(16) bf16_t p_lds[4 * 16 * 72];

  // XCD swizzle: 512 consecutive logical wgs (8 (b,h) pairs) per XCD.
  int wg = blockIdx.x;
  wg = (wg & 7) * 512 + (wg >> 3);
  const int b = wg >> 10;
  const int h = (wg >> 6) & 15;
  const int qt = wg & 63;
  const int blk = qt >> 2;
  const int wq = qt & 3;
  const int tid = threadIdx.x;
  const int wave = tid >> 6;
  const int lane = tid & 63;
  const int l15 = lane & 15;
  const int quad = lane >> 4;
  const int qw = qt * 64 + wave * 16;

  const size_t qoff = ((size_t)(b * 4096 + qw + l15)) * 3072 + h * 64;
  const bf16x8 qf0 = *(const bf16x8*)(qkv + qoff + quad * 8);
  const bf16x8 qf1 = *(const bf16x8*)(qkv + qoff + 32 + quad * 8);

  f32x4 of[4];
#pragma unroll
  for (int i = 0; i < 4; ++i) of[i] = (f32x4){0.f, 0.f, 0.f, 0.f};
  float m_i[4], l_i[4];
#pragma unroll
  for (int r = 0; r < 4; ++r) {
    m_i[r] = -1e30f;
    l_i[r] = 0.0f;
  }

  const int kb0 = blk * 256 - 256;
  const int kclo = (blk == 0) ? 4 : wq;
  const int kchi = wq + 4;

  const int row0 = tid >> 3;
  const int co8 = (tid & 7) * 8;
  const bf16_t* kbase = qkv + ((size_t)b * 4096) * 3072 + 1024 + h * 64;
  const bf16_t* vbase = vT + (((size_t)b * 16 + h) * 64) * 4096;
  uint4 kr0, kr1, vr0, vr1;

#define ISSUE_KV(KB)                                                           \
  do {                                                                         \
    kr0 = *(const uint4*)(kbase + (size_t)((KB) + row0) * 3072 + co8);         \
    kr1 = *(const uint4*)(kbase + (size_t)((KB) + row0 + 32) * 3072 + co8);    \
    vr0 = *(const uint4*)(vbase + (size_t)row0 * 4096 + (KB) + co8);           \
    vr1 = *(const uint4*)(vbase + (size_t)(row0 + 32) * 4096 + (KB) + co8);    \
  } while (0)

  ISSUE_KV(kb0 + kclo * 64);

  for (int kc = kclo; kc <= kchi; ++kc) {
    const int kb = kb0 + kc * 64;
    __syncthreads();  // prev chunk's PV reads done -> LDS reusable
    *(uint4*)(k_lds + row0 * 72 + co8) = kr0;
    *(uint4*)(k_lds + (row0 + 32) * 72 + co8) = kr1;
    *(uint4*)(vt_lds + row0 * 72 + co8) = vr0;
    *(uint4*)(vt_lds + (row0 + 32) * 72 + co8) = vr1;
    if (kc < kchi) ISSUE_KV(kb + 64);  // in flight under QK+softmax+PV
    __syncthreads();

    f32x4 s[4];
    __builtin_amdgcn_s_setprio(1);
#pragma unroll
    for (int nt = 0; nt < 4; ++nt) {
      bf16x8 kf0 = *(const bf16x8*)(k_lds + (nt * 16 + l15) * 72 + quad * 8);
      bf16x8 kf1 = *(const bf16x8*)(k_lds + (nt * 16 + l15) * 72 + 32 + quad * 8);
      f32x4 z = (f32x4){0.f, 0.f, 0.f, 0.f};
      z = MFMA_16x16x32(qf0, kf0, z);
      z = MFMA_16x16x32(qf1, kf1, z);
      s[nt] = z;
    }
    __builtin_amdgcn_s_setprio(0);

    float sv[4][4];
#pragma unroll
    for (int nt = 0; nt < 4; ++nt) {
      const int key = kb + nt * 16 + l15;
#pragma unroll
      for (int r = 0; r < 4; ++r) {
        const int p = qw + quad * 4 + r;
        const bool valid = (key <= p) && (key + 256 > p);
        sv[nt][r] = valid ? s[nt][r] * 0.125f : -1e30f;
      }
    }
    float rm[4];
#pragma unroll
    for (int r = 0; r < 4; ++r)
      rm[r] = fmaxf(fmaxf(sv[0][r], sv[1][r]), fmaxf(sv[2][r], sv[3][r]));
#pragma unroll
    for (int off = 1; off < 16; off <<= 1)
#pragma unroll
      for (int r = 0; r < 4; ++r) rm[r] = fmaxf(rm[r], __shfl_xor(rm[r], off));

    float mn[4], alpha[4];
#pragma unroll
    for (int r = 0; r < 4; ++r) {
      mn[r] = fmaxf(m_i[r], rm[r]);
      alpha[r] = __expf(m_i[r] - mn[r]);
      m_i[r] = mn[r];
    }

    float rs[4] = {0.f, 0.f, 0.f, 0.f};
#pragma unroll
    for (int nt = 0; nt < 4; ++nt)
#pragma unroll
      for (int r = 0; r < 4; ++r) {
        const float pv = (sv[nt][r] > -1e29f) ? __expf(sv[nt][r] - mn[r]) : 0.0f;
        rs[r] += pv;
        p_lds[wave * 1152 + (quad * 4 + r) * 72 + nt * 16 + l15] = (bf16_t)pv;
      }
#pragma unroll
    for (int off = 1; off < 16; off <<= 1)
#pragma unroll
      for (int r = 0; r < 4; ++r) rs[r] += __shfl_xor(rs[r], off);
#pragma unroll
    for (int r = 0; r < 4; ++r) l_i[r] = l_i[r] * alpha[r] + rs[r];
#pragma unroll
    for (int dt = 0; dt < 4; ++dt)
#pragma unroll
      for (int r = 0; r < 4; ++r) of[dt][r] *= alpha[r];

    // p_lds slice is wave-private (write->read same wave, lgkmcnt-ordered);
    // vt_lds was made visible by the post-staging barrier. No barrier here.
    __builtin_amdgcn_s_setprio(1);
#pragma unroll
    for (int kk = 0; kk < 2; ++kk) {
      bf16x8 pf = *(const bf16x8*)(p_lds + wave * 1152 + l15 * 72 + kk * 32 + quad * 8);
#pragma unroll
      for (int dt = 0; dt < 4; ++dt) {
        bf16x8 vf = *(const bf16x8*)(vt_lds + (dt * 16 + l15) * 72 + kk * 32 + quad * 8);
        of[dt] = MFMA_16x16x32(pf, vf, of[dt]);
      }
    }
    __builtin_amdgcn_s_setprio(0);
  }
#undef ISSUE_KV

  float inv[4];
#pragma unroll
  for (int r = 0; r < 4; ++r) inv[r] = 1.0f / fmaxf(l_i[r], 1e-20f);
  bf16_t* op = qkv + ((size_t)(b * 4096 + qw)) * 3072 + h * 64;  // overwrite Q cols
#pragma unroll
  for (int dt = 0; dt < 4; ++dt)
#pragma unroll
    for (int r = 0; r < 4; ++r)
      op[(size_t)(quad * 4 + r) * 3072 + dt * 16 + l15] = (bf16_t)(of[dt][r] * inv[r]);
}

// ---------------------------------------------------------------------------
extern "C" void kernel_launch(void* const* d_in, const int* in_sizes, int n_in,
                              void* d_out, int out_size, void* d_ws, size_t ws_size,
                              hipStream_t stream) {
  char* ws = (char*)d_ws;
  bf16_t* wTq = (bf16_t*)(ws);                    // [3072][1024]   6,291,456 B
  bf16_t* wTo = (bf16_t*)(ws + 6291456);          // [1024][1024]   2,097,152 B
  bf16_t* qkv = (bf16_t*)(ws + 8388608);          // [16384][3072] 100,663,296 B
  int* flag = (int*)(ws + 109051904);             // 4 B (total 109,051,908 B)

  bf16_t* xb = (bf16_t*)d_out;                    // converted x, [0, 32MB)
  bf16_t* vTb = (bf16_t*)((char*)d_out + 33554432);  // vT, [32MB, 64MB)
  // xb consumed by QKV GEMM (which writes vT into the other half of d_out);
  // vT consumed by attention; final GEMM overwrites all of d_out with f32.

  detect_dtype<<<1, 256, 0, stream>>>((const ushort_t*)d_in[0], flag);
  convert_to_bf16<<<1024, 256, 0, stream>>>(d_in[0], xb, 2097152, flag);
  transpose_cvt<<<dim3(48, 16), 256, 0, stream>>>(d_in[1], (ushort_t*)wTq, 1024, 3072,
                                                  flag);
  transpose_cvt<<<dim3(16, 16), 256, 0, stream>>>(d_in[2], (ushort_t*)wTo, 1024, 1024,
                                                  flag);
  // QKV GEMM with fused V-transpose (V cols -> vTb, Q/K cols -> qkv)
  gemm_qkv<<<dim3(12, 64), 512, 0, stream>>>(xb, 1024, wTq, qkv, 3072, 1024, vTb);
  attn_swa<<<dim3(4096), 256, 0, stream>>>(qkv, vTb);
  gemm_outp<<<dim3(4, 64), 512, 0, stream>>>(qkv, 3072, wTo, d_out, 1024, 1024, flag);
}